// Round 10
// baseline (10778.808 us; speedup 1.0000x reference)
//
#include <hip/hip_runtime.h>
#include <math.h>

#define T_STEPS 2048
#define BATCH   32
#define IN_DIM  512
#define H_DIM   512
#define G4      2048
#define NWG     16
#define NTHR    512

typedef __attribute__((ext_vector_type(8))) short short8;
typedef __attribute__((ext_vector_type(4))) float f32x4;
typedef __attribute__((ext_vector_type(2))) float f32x2;
typedef __attribute__((ext_vector_type(4))) unsigned u32x4;

__device__ inline unsigned short f2bf(float f) {
    unsigned u = __builtin_bit_cast(unsigned, f);
    unsigned r = (u + 0x7FFFu + ((u >> 16) & 1u)) >> 16;
    return (unsigned short)r;
}
__device__ inline unsigned pack2(float a, float b) {
    return (unsigned)f2bf(a) | ((unsigned)f2bf(b) << 16);
}
__device__ inline float h2f(unsigned u) {
    _Float16 h = __builtin_bit_cast(_Float16, (unsigned short)(u & 0xFFFFu));
    return (float)h;
}
// fast transcendentals: v_exp_f32 / v_rcp_f32 (~2 ulp; bf16 noise dominates)
__device__ inline float fsigm(float x) {
    return __builtin_amdgcn_rcpf(1.f + __expf(-x));
}
__device__ inline float ftanh(float x) {
    return 1.f - 2.f * __builtin_amdgcn_rcpf(__expf(2.f * x) + 1.f);
}
__device__ inline float sigm(float v) { return 1.f / (1.f + expf(-v)); }  // fallback

// 4 parallel IC-coherent 16B loads + drain (R4-proven)
__device__ inline void ld4x_ic(const void* p0, const void* p1,
                               const void* p2, const void* p3,
                               u32x4& v0, u32x4& v1, u32x4& v2, u32x4& v3) {
    asm volatile(
        "global_load_dwordx4 %0, %4, off sc1\n\t"
        "global_load_dwordx4 %1, %5, off sc1\n\t"
        "global_load_dwordx4 %2, %6, off sc1\n\t"
        "global_load_dwordx4 %3, %7, off sc1\n\t"
        "s_waitcnt vmcnt(0)"
        : "=&v"(v0), "=&v"(v1), "=&v"(v2), "=&v"(v3)
        : "v"(p0), "v"(p1), "v"(p2), "v"(p3) : "memory");
}

// ---------------------------------------------------------------------------
// W [1024][2048] fp32 -> Wt [2048][1024] bf16 (transposed; k<512 = x-part)
// ---------------------------------------------------------------------------
__global__ __launch_bounds__(256) void wt_kernel(const float* __restrict__ W,
                                                 unsigned short* __restrict__ Wt) {
    __shared__ unsigned short tile[32][33];
    const int n0 = blockIdx.x << 5, k0 = blockIdx.y << 5;
    const int tx = threadIdx.x & 31, ty = threadIdx.x >> 5;
    #pragma unroll
    for (int r = 0; r < 32; r += 8)
        tile[ty + r][tx] = f2bf(W[(size_t)(k0 + ty + r) * G4 + n0 + tx]);
    __syncthreads();
    #pragma unroll
    for (int r = 0; r < 32; r += 8)
        Wt[(size_t)(n0 + ty + r) * 1024 + k0 + tx] = tile[tx][ty + r];
}

__global__ void init_h(const float* __restrict__ h0, unsigned short* __restrict__ hb) {
    int i = blockIdx.x * 256 + threadIdx.x;   // 16384 total
    hb[i] = f2bf(h0[i]);
}

// ---------------------------------------------------------------------------
// Phase 1 (full T): pre16[m][col] = fp16(x[m][:] @ W[0:512][col] + bias[col]).
// M=65536, N=2048, K=512. BM=BN=64, BK=32, 4 waves. (R2/R4/R8-proven core)
// ---------------------------------------------------------------------------
__global__ __launch_bounds__(256) void xw_mfma(const float* __restrict__ x,
                                               const unsigned short* __restrict__ Wt,
                                               const float* __restrict__ bias,
                                               _Float16* __restrict__ pre16) {
    __shared__ unsigned short As[64][40];   // row stride 80B (16B-aligned)
    __shared__ unsigned short Bs[64][40];
    const int tid = threadIdx.x;
    const int w = tid >> 6, l = tid & 63;
    const int m0 = blockIdx.y << 6, n0 = blockIdx.x << 6;
    const int srow = tid >> 2, sseg = (tid & 3) << 3;
    const int arow = (w << 4) + (l & 15);
    const int kb = (l >> 4) << 3;
    f32x4 acc[4] = {};

    for (int kc = 0; kc < 16; ++kc) {
        const float* xs = x + (size_t)(m0 + srow) * IN_DIM + kc * 32 + sseg;
        float4 xa = *(const float4*)xs;
        float4 xb2 = *(const float4*)(xs + 4);
        int4 av;
        av.x = pack2(xa.x, xa.y);  av.y = pack2(xa.z, xa.w);
        av.z = pack2(xb2.x, xb2.y); av.w = pack2(xb2.z, xb2.w);
        *(int4*)&As[srow][sseg] = av;
        *(int4*)&Bs[srow][sseg] = *(const int4*)(Wt + (size_t)(n0 + srow) * 1024 + kc * 32 + sseg);
        __syncthreads();
        short8 af = *(const short8*)&As[arow][kb];
        #pragma unroll
        for (int n = 0; n < 4; ++n) {
            short8 bf = *(const short8*)&Bs[(n << 4) + (l & 15)][kb];
            acc[n] = __builtin_amdgcn_mfma_f32_16x16x32_bf16(af, bf, acc[n], 0, 0, 0);
        }
        __syncthreads();
    }
    #pragma unroll
    for (int n = 0; n < 4; ++n) {
        const int col = n0 + (n << 4) + (l & 15);
        const float bb = bias[col];
        #pragma unroll
        for (int ri = 0; ri < 4; ++ri) {
            const int row = m0 + (w << 4) + ((l >> 4) << 2) + ri;
            pre16[(size_t)row * G4 + col] = (_Float16)(acc[n][ri] + bb);
        }
    }
}

// ---------------------------------------------------------------------------
// Persistent scan, SINGLE dispatch, operand-swap MFMA.
// 16 WGs x 512 thr (8 waves). WG g owns hidden cols [g*32,(g+1)*32).
// Wave w owns 4 hidden cols (w*4..w*4+3): A = W rows interleaved {f,i,g,o} per
// hc -> each lane's acc = all 4 gates of ONE (hc,b) cell; update is pure
// in-register (no gates LDS). h exchanged via proven sc1-IC protocol;
// barrier = per-WG slots + 16-lane sc1 poll (R8/R9 proven, unchanged).
// ---------------------------------------------------------------------------
__global__ __launch_bounds__(NTHR, 1) void lstm_scan(
        const unsigned short* __restrict__ Wt,   // [2048][1024], h-part at k+512
        const _Float16* __restrict__ pre16,      // [65536][2048], bias included
        const float* __restrict__ c0,            // [32][512]
        unsigned short* __restrict__ hbuf,       // [2][32][512] bf16, [0] init'd
        float* __restrict__ outs,                // [2048][32][512]
        float* __restrict__ hf, float* __restrict__ cf,
        unsigned int* __restrict__ flags) {      // 16 slots, 64B apart
    __shared__ char Hl[32768];   // h: 32 rows (b) x 1KB, XOR-swizzled

    const int g = blockIdx.x;
    const int tid = threadIdx.x;
    const int w = tid >> 6, l = tid & 63;

    // --- A-operand (W_h) fragments: lane holds A[m=l&15][k=(l>>4)*8+j].
    // m-row r interleaves gates: r = 4*hcl + q  ->  gatecol = q*512 + g*32 + w*4 + hcl
    const int rA = l & 15;
    const int gcolA = ((rA & 3) << 9) + (g << 5) + (w << 2) + (rA >> 2);
    const int ksub = (l >> 4) << 3;
    short8 wfh[16];
    #pragma unroll
    for (int kc = 0; kc < 16; ++kc)
        wfh[kc] = *(const short8*)(Wt + (size_t)gcolA * 1024 + 512 + kc * 32 + ksub);

    // --- per-lane cell ownership (C layout: row=(l>>4)*4+ri, col=l&15)
    const int hc = (g << 5) + (w << 2) + (l >> 4);   // hidden col
    const int b  = l & 15;                           // batch (acc0); acc1 -> b+16
    float cv0 = c0[(b << 9) + hc];
    float cv1 = c0[((b + 16) << 9) + hc];

    // --- staging / ds-read indices (identical to proven rounds)
    const int arow0 = l & 15, arow1 = (l & 15) + 16;
    const int kbyte = (l >> 4) << 4;
    const int swz0 = (arow0 & 7) << 4, swz1 = (arow1 & 7) << 4;
    const int hcl_odd = (l >> 4) & 1;

    // --- stage h(0) -> Hl (IC loads; hbuf[0] from init_h)
    {
        const unsigned short* hp0 = hbuf + (w << 9) + (l << 3);
        u32x4 v0, v1, v2, v3;
        ld4x_ic(hp0, hp0 + 4096, hp0 + 8192, hp0 + 12288, v0, v1, v2, v3);
        char* hd = Hl + w * 1024 + ((l << 4) ^ (w << 4));
        *(u32x4*)hd = v0; *(u32x4*)(hd + 8192) = v1;
        *(u32x4*)(hd + 16384) = v2; *(u32x4*)(hd + 24576) = v3;
    }
    __syncthreads();

    // --- initial pre prefetch (t=0): 8 asm ushort loads (fp16 pre)
    const unsigned short* preu = (const unsigned short*)pre16;
    unsigned pu0, pu1, pu2, pu3, pu4, pu5, pu6, pu7;
    {
        const unsigned short* pb0 = preu + ((size_t)b << 11) + hc;
        const unsigned short* pb1 = preu + ((size_t)(b + 16) << 11) + hc;
        asm volatile("global_load_ushort %0, %1, off" : "=v"(pu0) : "v"(pb0) : "memory");
        asm volatile("global_load_ushort %0, %1, off" : "=v"(pu1) : "v"(pb0 + 512) : "memory");
        asm volatile("global_load_ushort %0, %1, off" : "=v"(pu2) : "v"(pb0 + 1024) : "memory");
        asm volatile("global_load_ushort %0, %1, off" : "=v"(pu3) : "v"(pb0 + 1536) : "memory");
        asm volatile("global_load_ushort %0, %1, off" : "=v"(pu4) : "v"(pb1) : "memory");
        asm volatile("global_load_ushort %0, %1, off" : "=v"(pu5) : "v"(pb1 + 512) : "memory");
        asm volatile("global_load_ushort %0, %1, off" : "=v"(pu6) : "v"(pb1 + 1024) : "memory");
        asm volatile("global_load_ushort %0, %1, off" : "=v"(pu7) : "v"(pb1 + 1536) : "memory");
    }

    for (int gt = 0; gt < T_STEPS; ++gt) {
        // A. MFMA: gates^T = Wfrag(A) @ h(B);  acc0 = batches 0..15, acc1 = 16..31
        f32x4 acc0 = {0.f, 0.f, 0.f, 0.f}, acc1 = {0.f, 0.f, 0.f, 0.f};
        #pragma unroll
        for (int kc = 0; kc < 16; ++kc) {
            const int kb2 = kc * 64 + kbyte;
            short8 hb0 = *(const short8*)(Hl + arow0 * 1024 + (kb2 ^ swz0));
            short8 hb1 = *(const short8*)(Hl + arow1 * 1024 + (kb2 ^ swz1));
            acc0 = __builtin_amdgcn_mfma_f32_16x16x32_bf16(wfh[kc], hb0, acc0, 0, 0, 0);
            acc1 = __builtin_amdgcn_mfma_f32_16x16x32_bf16(wfh[kc], hb1, acc1, 0, 0, 0);
        }

        // B. fence pre loads (steady-state: already drained -> free), then
        //    fully in-register update: acc = {f,i,g,o} of (hc, b / b+16)
        asm volatile("s_waitcnt vmcnt(0)" ::: "memory");
        __builtin_amdgcn_sched_barrier(0);
        const float f0 = fsigm(acc0[0] + h2f(pu0));
        const float i0 = fsigm(acc0[1] + h2f(pu1));
        const float g0 = ftanh(acc0[2] + h2f(pu2));
        const float o0 = fsigm(acc0[3] + h2f(pu3));
        cv0 = f0 * cv0 + i0 * g0;
        const float hn0 = o0 * ftanh(cv0);
        const float f1 = fsigm(acc1[0] + h2f(pu4));
        const float i1 = fsigm(acc1[1] + h2f(pu5));
        const float g1 = ftanh(acc1[2] + h2f(pu6));
        const float o1 = fsigm(acc1[3] + h2f(pu7));
        cv1 = f1 * cv1 + i1 * g1;
        const float hn1 = o1 * ftanh(cv1);

        // C. lane-pair pack via ds_swizzle (xor 16: partner has hc^1, same b):
        //    even hcl -> stores (hc,hc+1) for b; odd hcl -> for b+16.
        const float sw0 = __builtin_bit_cast(float,
            __builtin_amdgcn_ds_swizzle(__builtin_bit_cast(int, hn0), 0x401F));
        const float sw1 = __builtin_bit_cast(float,
            __builtin_amdgcn_ds_swizzle(__builtin_bit_cast(int, hn1), 0x401F));
        if (!hcl_odd) {
            float* op = outs + ((size_t)gt << 14) + (b << 9) + hc;   // hc even
            f32x2 ov; ov.x = hn0; ov.y = sw0;
            asm volatile("global_store_dwordx2 %0, %1, off" :: "v"(op), "v"(ov) : "memory");
            unsigned* hp = (unsigned*)(hbuf + (((gt + 1) & 1) << 14) + (b << 9) + hc);
            asm volatile("global_store_dword %0, %1, off sc1"
                         :: "v"(hp), "v"(pack2(hn0, sw0)) : "memory");
        } else {
            float* op = outs + ((size_t)gt << 14) + ((b + 16) << 9) + (hc - 1);
            f32x2 ov; ov.x = sw1; ov.y = hn1;
            asm volatile("global_store_dwordx2 %0, %1, off" :: "v"(op), "v"(ov) : "memory");
            unsigned* hp = (unsigned*)(hbuf + (((gt + 1) & 1) << 14) + ((b + 16) << 9) + (hc - 1));
            asm volatile("global_store_dword %0, %1, off sc1"
                         :: "v"(hp), "v"(pack2(sw1, hn1)) : "memory");
        }

        if (gt == T_STEPS - 1) {
            hf[(b << 9) + hc] = hn0;  hf[((b + 16) << 9) + hc] = hn1;
            cf[(b << 9) + hc] = cv0;  cf[((b + 16) << 9) + hc] = cv1;
            break;                              // no final barrier needed
        }

        // D. prefetch pre(gt+1): 8 ushort loads (drain at next stage/update)
        {
            const unsigned short* pb0 = preu + (((size_t)(gt + 1) << 5) + b) * 2048 + hc;
            const unsigned short* pb1 = pb0 + (16 << 11);
            asm volatile("global_load_ushort %0, %1, off" : "=v"(pu0) : "v"(pb0) : "memory");
            asm volatile("global_load_ushort %0, %1, off" : "=v"(pu1) : "v"(pb0 + 512) : "memory");
            asm volatile("global_load_ushort %0, %1, off" : "=v"(pu2) : "v"(pb0 + 1024) : "memory");
            asm volatile("global_load_ushort %0, %1, off" : "=v"(pu3) : "v"(pb0 + 1536) : "memory");
            asm volatile("global_load_ushort %0, %1, off" : "=v"(pu4) : "v"(pb1) : "memory");
            asm volatile("global_load_ushort %0, %1, off" : "=v"(pu5) : "v"(pb1 + 512) : "memory");
            asm volatile("global_load_ushort %0, %1, off" : "=v"(pu6) : "v"(pb1 + 1024) : "memory");
            asm volatile("global_load_ushort %0, %1, off" : "=v"(pu7) : "v"(pb1 + 1536) : "memory");
        }
        // E. drain the stores only (oldest-first; 8 loads stay in flight)
        asm volatile("s_waitcnt vmcnt(8)" ::: "memory");
        __builtin_amdgcn_sched_barrier(0);

        // F. grid barrier (R8/R9 proven): contention-free arrival + 16-lane poll
        __syncthreads();                 // (sync 1) all waves' stores drained
        if (tid == 0)
            atomicAdd(flags + (g << 4), 1u);
        if (tid < 16) {
            unsigned* slot = flags + (tid << 4);
            const unsigned tgt = (unsigned)(gt + 1);
            for (;;) {
                unsigned vb;
                asm volatile("global_load_dword %0, %1, off sc1\n\ts_waitcnt vmcnt(0)"
                             : "=v"(vb) : "v"(slot) : "memory");
                if (vb >= tgt) break;
            }
        }
        __syncthreads();                 // (sync 2) barrier passed

        // G. stage h(gt+1) -> Hl (IC-coherent; internal vmcnt(0) drains pre loads)
        {
            const unsigned short* hsrc = hbuf + (((gt + 1) & 1) << 14) + (w << 9) + (l << 3);
            u32x4 v0, v1, v2, v3;
            ld4x_ic(hsrc, hsrc + 4096, hsrc + 8192, hsrc + 12288, v0, v1, v2, v3);
            char* hd = Hl + w * 1024 + ((l << 4) ^ (w << 4));
            *(u32x4*)hd = v0; *(u32x4*)(hd + 8192) = v1;
            *(u32x4*)(hd + 16384) = v2; *(u32x4*)(hd + 24576) = v3;
        }
        __syncthreads();                 // (sync 3) Hl ready
    }
}

// ---------------------------------------------------------------------------
// Minimal fallback (tiny ws): 2048 step launches, fp32, x folded in.
// ---------------------------------------------------------------------------
__global__ __launch_bounds__(256) void lstm_step(const float* __restrict__ x_t,
                                                 const float* __restrict__ h_prev,
                                                 const float* __restrict__ W,
                                                 const float* __restrict__ bias,
                                                 const float* __restrict__ c_in,
                                                 float* __restrict__ c_out,
                                                 float* __restrict__ h_out,
                                                 float* __restrict__ hf,
                                                 float* __restrict__ cf, int last) {
    const int tid = threadIdx.x;
    const int hcc = tid & 7, b = tid >> 3;
    const int col = blockIdx.x * 8 + hcc;
    float a0 = bias[col], a1 = bias[col + 512], a2 = bias[col + 1024], a3 = bias[col + 1536];
    const float* xr = x_t + (size_t)b * IN_DIM;
    const float* hr = h_prev + (size_t)b * H_DIM;
    for (int k = 0; k < IN_DIM; ++k) {
        const float v = xr[k];
        const float* wk = &W[(size_t)k * G4 + col];
        a0 += v * wk[0]; a1 += v * wk[512]; a2 += v * wk[1024]; a3 += v * wk[1536];
    }
    for (int k = 0; k < H_DIM; ++k) {
        const float v = hr[k];
        const float* wk = &W[(size_t)(512 + k) * G4 + col];
        a0 += v * wk[0]; a1 += v * wk[512]; a2 += v * wk[1024]; a3 += v * wk[1536];
    }
    const float cn = sigm(a0) * c_in[(size_t)b * H_DIM + col] + sigm(a1) * tanhf(a2);
    const float hn = sigm(a3) * tanhf(cn);
    c_out[(size_t)b * H_DIM + col] = cn;
    h_out[(size_t)b * H_DIM + col] = hn;
    if (last) { hf[(size_t)b * H_DIM + col] = hn; cf[(size_t)b * H_DIM + col] = cn; }
}

extern "C" void kernel_launch(void* const* d_in, const int* in_sizes, int n_in,
                              void* d_out, int out_size, void* d_ws, size_t ws_size,
                              hipStream_t stream) {
    const float* x    = (const float*)d_in[0];
    const float* h0   = (const float*)d_in[1];
    const float* c0   = (const float*)d_in[2];
    const float* W    = (const float*)d_in[3];
    const float* bias = (const float*)d_in[4];

    float* outs = (float*)d_out;
    float* hf   = outs + (size_t)T_STEPS * BATCH * H_DIM;
    float* cf   = hf + BATCH * H_DIM;

    // pre16 (fp16, full T): 256 MiB  + Wt 4 MiB + hbuf 64 KiB + flags 4 KiB
    const size_t OFF_WT = 268435456ull;            // pre16: [65536][2048] fp16
    const size_t OFF_HB = OFF_WT + 4194304ull;     // Wt: 4 MiB
    const size_t OFF_FL = OFF_HB + 65536ull;       // hbuf: 64 KiB
    const size_t NEED   = OFF_FL + 4096ull;        // ~272.7 MB << proven 536.9 MB

    if (ws_size >= NEED) {
        _Float16* pre16     = (_Float16*)d_ws;
        unsigned short* Wt  = (unsigned short*)((char*)d_ws + OFF_WT);
        unsigned short* hb  = (unsigned short*)((char*)d_ws + OFF_HB);
        unsigned int* flags = (unsigned int*)((char*)d_ws + OFF_FL);

        hipMemsetAsync(flags, 0, 4096, stream);
        wt_kernel<<<dim3(64, 32), 256, 0, stream>>>(W, Wt);
        init_h<<<64, 256, 0, stream>>>(h0, hb);
        xw_mfma<<<dim3(32, 1024), 256, 0, stream>>>(x, Wt, bias, pre16);
        lstm_scan<<<NWG, NTHR, 0, stream>>>(Wt, pre16, c0, hb, outs, hf, cf, flags);
    } else {
        float* c_ws = (float*)d_ws;
        for (int t = 0; t < T_STEPS; ++t) {
            const float* hp = t ? outs + (size_t)(t - 1) * BATCH * H_DIM : h0;
            const float* ci = t ? c_ws : c0;
            lstm_step<<<64, 256, 0, stream>>>(x + (size_t)t * BATCH * IN_DIM,
                                              hp, W, bias, ci, c_ws,
                                              outs + (size_t)t * BATCH * H_DIM,
                                              hf, cf, (t == T_STEPS - 1) ? 1 : 0);
        }
    }
}

// Round 13
// 7363.317 us; speedup vs baseline: 1.4639x; 1.4639x over previous
//
#include <hip/hip_runtime.h>
#include <math.h>

#define T_STEPS 2048
#define BATCH   32
#define IN_DIM  512
#define H_DIM   512
#define G4      2048
#define NWG     16
#define NTHR    512
#define GLS     132      // gates LDS row stride (floats), padded

typedef __attribute__((ext_vector_type(8))) short short8;
typedef __attribute__((ext_vector_type(4))) float f32x4;
typedef __attribute__((ext_vector_type(2))) float f32x2;
typedef __attribute__((ext_vector_type(4))) unsigned u32x4;

__device__ inline unsigned short f2bf(float f) {
    unsigned u = __builtin_bit_cast(unsigned, f);
    unsigned r = (u + 0x7FFFu + ((u >> 16) & 1u)) >> 16;
    return (unsigned short)r;
}
__device__ inline unsigned pack2(float a, float b) {
    return (unsigned)f2bf(a) | ((unsigned)f2bf(b) << 16);
}
__device__ inline float h2f(unsigned u) {
    _Float16 h = __builtin_bit_cast(_Float16, (unsigned short)(u & 0xFFFFu));
    return (float)h;
}
// fast transcendentals: v_exp_f32 / v_rcp_f32 (~2 ulp; bf16 noise dominates)
__device__ inline float fsigm(float x) {
    return __builtin_amdgcn_rcpf(1.f + __expf(-x));
}
__device__ inline float ftanh(float x) {
    return 1.f - 2.f * __builtin_amdgcn_rcpf(__expf(2.f * x) + 1.f);
}
__device__ inline float sigm(float v) { return 1.f / (1.f + expf(-v)); }  // fallback

// 4 parallel IC-coherent 16B loads + drain (R4-proven)
__device__ inline void ld4x_ic(const void* p0, const void* p1,
                               const void* p2, const void* p3,
                               u32x4& v0, u32x4& v1, u32x4& v2, u32x4& v3) {
    asm volatile(
        "global_load_dwordx4 %0, %4, off sc1\n\t"
        "global_load_dwordx4 %1, %5, off sc1\n\t"
        "global_load_dwordx4 %2, %6, off sc1\n\t"
        "global_load_dwordx4 %3, %7, off sc1\n\t"
        "s_waitcnt vmcnt(0)"
        : "=&v"(v0), "=&v"(v1), "=&v"(v2), "=&v"(v3)
        : "v"(p0), "v"(p1), "v"(p2), "v"(p3) : "memory");
}

// ---------------------------------------------------------------------------
// W [1024][2048] fp32 -> Wt [2048][1024] bf16 (transposed; k<512 = x-part)
// ---------------------------------------------------------------------------
__global__ __launch_bounds__(256) void wt_kernel(const float* __restrict__ W,
                                                 unsigned short* __restrict__ Wt) {
    __shared__ unsigned short tile[32][33];
    const int n0 = blockIdx.x << 5, k0 = blockIdx.y << 5;
    const int tx = threadIdx.x & 31, ty = threadIdx.x >> 5;
    #pragma unroll
    for (int r = 0; r < 32; r += 8)
        tile[ty + r][tx] = f2bf(W[(size_t)(k0 + ty + r) * G4 + n0 + tx]);
    __syncthreads();
    #pragma unroll
    for (int r = 0; r < 32; r += 8)
        Wt[(size_t)(n0 + ty + r) * 1024 + k0 + tx] = tile[tx][ty + r];
}

__global__ void init_h(const float* __restrict__ h0, unsigned short* __restrict__ hb) {
    int i = blockIdx.x * 256 + threadIdx.x;   // 16384 total
    hb[i] = f2bf(h0[i]);
}

// ---------------------------------------------------------------------------
// Phase 1 (full T): pre16[m][col] = fp16(x[m][:] @ W[0:512][col] + bias[col]).
// M=65536, N=2048, K=512. BM=BN=64, BK=32, 4 waves. (R2/R4/R8/R9-proven core;
// only the output store dtype changed fp32->fp16.)
// ---------------------------------------------------------------------------
__global__ __launch_bounds__(256) void xw_mfma(const float* __restrict__ x,
                                               const unsigned short* __restrict__ Wt,
                                               const float* __restrict__ bias,
                                               _Float16* __restrict__ pre16) {
    __shared__ unsigned short As[64][40];   // row stride 80B (16B-aligned)
    __shared__ unsigned short Bs[64][40];
    const int tid = threadIdx.x;
    const int w = tid >> 6, l = tid & 63;
    const int m0 = blockIdx.y << 6, n0 = blockIdx.x << 6;
    const int srow = tid >> 2, sseg = (tid & 3) << 3;
    const int arow = (w << 4) + (l & 15);
    const int kb = (l >> 4) << 3;
    f32x4 acc[4] = {};

    for (int kc = 0; kc < 16; ++kc) {
        const float* xs = x + (size_t)(m0 + srow) * IN_DIM + kc * 32 + sseg;
        float4 xa = *(const float4*)xs;
        float4 xb2 = *(const float4*)(xs + 4);
        int4 av;
        av.x = pack2(xa.x, xa.y);  av.y = pack2(xa.z, xa.w);
        av.z = pack2(xb2.x, xb2.y); av.w = pack2(xb2.z, xb2.w);
        *(int4*)&As[srow][sseg] = av;
        *(int4*)&Bs[srow][sseg] = *(const int4*)(Wt + (size_t)(n0 + srow) * 1024 + kc * 32 + sseg);
        __syncthreads();
        short8 af = *(const short8*)&As[arow][kb];
        #pragma unroll
        for (int n = 0; n < 4; ++n) {
            short8 bf = *(const short8*)&Bs[(n << 4) + (l & 15)][kb];
            acc[n] = __builtin_amdgcn_mfma_f32_16x16x32_bf16(af, bf, acc[n], 0, 0, 0);
        }
        __syncthreads();
    }
    #pragma unroll
    for (int n = 0; n < 4; ++n) {
        const int col = n0 + (n << 4) + (l & 15);
        const float bb = bias[col];
        #pragma unroll
        for (int ri = 0; ri < 4; ++ri) {
            const int row = m0 + (w << 4) + ((l >> 4) << 2) + ri;
            pre16[(size_t)row * G4 + col] = (_Float16)(acc[n][ri] + bb);
        }
    }
}

// ---------------------------------------------------------------------------
// Persistent scan, SINGLE dispatch, R9's PROVEN sync throughout:
// 16 WGs x 512 thr (8 waves). WG g owns hidden cols [g*32,(g+1)*32) -> 128
// gate cols. W_h frags in VGPRs; h via sc1 IC exchange (pack2 bf16 stores +
// ld4x_ic staging); barrier = per-WG 64B slots (contention-free atomicAdd) +
// 16-lane sc1 poll. c in registers for the whole scan. Changes vs R9: fp16
// pre (4 dword pair-loads), h-store issued before outs-store with vmcnt(5)
// (drains only the h store at the barrier).
// ---------------------------------------------------------------------------
__global__ __launch_bounds__(NTHR, 1) void lstm_scan(
        const unsigned short* __restrict__ Wt,     // [2048][1024], h-part at k+512
        const unsigned short* __restrict__ pre16u, // [65536][2048] fp16, bias incl.
        const float* __restrict__ c0,              // [32][512]
        unsigned short* __restrict__ hbuf,         // [2][32][512] bf16, [0] init'd
        float* __restrict__ outs,                  // [2048][32][512]
        float* __restrict__ hf, float* __restrict__ cf,
        unsigned int* __restrict__ flags) {        // 16 slots, 64B apart
    __shared__ char Hl[32768];        // h: 32 rows x 1KB, swizzled
    __shared__ float Gl[32 * GLS];    // gates: separate region (16.9KB)

    const int g = blockIdx.x;
    const int tid = threadIdx.x;
    const int w = tid >> 6, l = tid & 63;

    // --- W_h fragments: wave w -> global gate cols gc (16 cols/wave)
    const int gc = ((w >> 1) << 9) + (g << 5) + ((w & 1) << 4) + (l & 15);
    const int ksub = (l >> 4) << 3;
    short8 wfh[16];
    #pragma unroll
    for (int kc = 0; kc < 16; ++kc)
        wfh[kc] = *(const short8*)(Wt + (size_t)gc * 1024 + 512 + kc * 32 + ksub);

    // --- update-phase mapping: thread -> (b, even col pair)
    const int b   = tid >> 4;
    const int hcp = (tid & 15) << 1;
    const int col = (g << 5) + hcp;
    float2 cv = *(const float2*)(c0 + (b << 9) + col);

    const int arow0 = l & 15, arow1 = (l & 15) + 16;
    const int kbyte = (l >> 4) << 4;
    const int swz0 = (arow0 & 7) << 4, swz1 = (arow1 & 7) << 4;
    const int lcw = (w << 4) + (l & 15);

    // --- stage h(0) -> Hl (IC loads; hbuf[0] from init_h)
    {
        const unsigned short* hp0 = hbuf + (w << 9) + (l << 3);
        u32x4 v0, v1, v2, v3;
        ld4x_ic(hp0, hp0 + 4096, hp0 + 8192, hp0 + 12288, v0, v1, v2, v3);
        char* hd = Hl + w * 1024 + ((l << 4) ^ (w << 4));
        *(u32x4*)hd = v0; *(u32x4*)(hd + 8192) = v1;
        *(u32x4*)(hd + 16384) = v2; *(u32x4*)(hd + 24576) = v3;
    }
    __syncthreads();

    // --- initial pre prefetch (gt=0): 4 coalesced fp16-pair dwords
    unsigned puf, pui, pug, puo;
    {
        const unsigned* pp = (const unsigned*)(pre16u + ((size_t)b << 11) + col);
        asm volatile("global_load_dword %0, %4, off\n\t"
                     "global_load_dword %1, %4, off offset:1024\n\t"
                     "global_load_dword %2, %4, off offset:2048\n\t"
                     "global_load_dword %3, %4, off offset:3072"
                     : "=&v"(puf), "=&v"(pui), "=&v"(pug), "=&v"(puo)
                     : "v"(pp) : "memory");
    }

    for (int gt = 0; gt < T_STEPS; ++gt) {
        // A. MFMA: h[32,512] @ Wh[512,16/wave] -> gates
        f32x4 acc0 = {0.f, 0.f, 0.f, 0.f}, acc1 = {0.f, 0.f, 0.f, 0.f};
        #pragma unroll
        for (int kc = 0; kc < 16; ++kc) {
            const int kb2 = kc * 64 + kbyte;
            short8 ha0 = *(const short8*)(Hl + arow0 * 1024 + (kb2 ^ swz0));
            short8 ha1 = *(const short8*)(Hl + arow1 * 1024 + (kb2 ^ swz1));
            acc0 = __builtin_amdgcn_mfma_f32_16x16x32_bf16(ha0, wfh[kc], acc0, 0, 0, 0);
            acc1 = __builtin_amdgcn_mfma_f32_16x16x32_bf16(ha1, wfh[kc], acc1, 0, 0, 0);
        }

        // B. gates -> Gl (separate region)
        #pragma unroll
        for (int ri = 0; ri < 4; ++ri) {
            const int br = ((l >> 4) << 2) + ri;
            Gl[br * GLS + lcw] = acc0[ri];
            Gl[(br + 16) * GLS + lcw] = acc1[ri];
        }
        __syncthreads();                 // (sync 1) gates visible

        // C. pre loads (issued last iter) now required
        asm volatile("s_waitcnt vmcnt(0)" ::: "memory");
        __builtin_amdgcn_sched_barrier(0);

        // D. elementwise update (fast transcendentals, fp16 pre unpack)
        const float* grow = Gl + b * GLS + hcp;
        const float2 g_f = *(const float2*)(grow);
        const float2 g_i = *(const float2*)(grow + 32);
        const float2 g_g = *(const float2*)(grow + 64);
        const float2 g_o = *(const float2*)(grow + 96);
        const float f0 = fsigm(g_f.x + h2f(puf)), f1 = fsigm(g_f.y + h2f(puf >> 16));
        const float i0 = fsigm(g_i.x + h2f(pui)), i1 = fsigm(g_i.y + h2f(pui >> 16));
        const float g0 = ftanh(g_g.x + h2f(pug)), g1 = ftanh(g_g.y + h2f(pug >> 16));
        const float o0 = fsigm(g_o.x + h2f(puo)), o1 = fsigm(g_o.y + h2f(puo >> 16));
        cv.x = f0 * cv.x + i0 * g0;
        cv.y = f1 * cv.y + i1 * g1;
        const float hn0 = o0 * ftanh(cv.x);
        const float hn1 = o1 * ftanh(cv.y);

        // E. stores: h for next step FIRST (sc1), then outs (plain)
        {
            unsigned* hdst = (unsigned*)hbuf + (((gt + 1) & 1) << 13) + (b << 8) + (col >> 1);
            const unsigned pk = pack2(hn0, hn1);
            asm volatile("global_store_dword %0, %1, off sc1" :: "v"(hdst), "v"(pk) : "memory");
            float* optr = outs + ((size_t)gt << 14) + (b << 9) + col;
            f32x2 ov; ov.x = hn0; ov.y = hn1;
            asm volatile("global_store_dwordx2 %0, %1, off" :: "v"(optr), "v"(ov) : "memory");
        }
        if (gt == T_STEPS - 1) {
            *(float2*)(hf + (b << 9) + col) = make_float2(hn0, hn1);
            *(float2*)(cf + (b << 9) + col) = make_float2(cv.x, cv.y);
            break;                              // no final barrier needed
        }

        // G. issue pre prefetch for gt+1 (after the stores)
        {
            const unsigned* pp = (const unsigned*)
                (pre16u + (((size_t)(gt + 1) << 5) + b) * 2048 + col);
            asm volatile("global_load_dword %0, %4, off\n\t"
                         "global_load_dword %1, %4, off offset:1024\n\t"
                         "global_load_dword %2, %4, off offset:2048\n\t"
                         "global_load_dword %3, %4, off offset:3072"
                         : "=&v"(puf), "=&v"(pui), "=&v"(pug), "=&v"(puo)
                         : "v"(pp) : "memory");
        }
        // H. drain ONLY the h store (oldest). outs store + 4 loads in flight.
        asm volatile("s_waitcnt vmcnt(5)" ::: "memory");

        // I. grid barrier (R8/R9 proven): contention-free arrival, 16-lane poll
        __syncthreads();                 // (sync 2) all waves' h stores drained
        if (tid == 0)
            atomicAdd(flags + (g << 4), 1u);    // slot value = steps done
        if (tid < 16) {
            unsigned* slot = flags + (tid << 4);
            const unsigned tgt = (unsigned)(gt + 1);
            for (;;) {
                unsigned vb;
                asm volatile("global_load_dword %0, %1, off sc1\n\ts_waitcnt vmcnt(0)"
                             : "=v"(vb) : "v"(slot) : "memory");
                if (vb >= tgt) break;
            }
        }
        __syncthreads();                 // (sync 3) barrier passed

        // L. stage h(gt+1) -> Hl (IC-coherent)
        {
            const unsigned short* hsrc = hbuf + (((gt + 1) & 1) << 14) + (w << 9) + (l << 3);
            u32x4 v0, v1, v2, v3;
            ld4x_ic(hsrc, hsrc + 4096, hsrc + 8192, hsrc + 12288, v0, v1, v2, v3);
            char* hd = Hl + w * 1024 + ((l << 4) ^ (w << 4));
            *(u32x4*)hd = v0; *(u32x4*)(hd + 8192) = v1;
            *(u32x4*)(hd + 16384) = v2; *(u32x4*)(hd + 24576) = v3;
        }
        __syncthreads();                 // (sync 4) Hl ready
    }
}

// ---------------------------------------------------------------------------
// Minimal fallback (tiny ws): 2048 step launches, fp32, x folded in.
// ---------------------------------------------------------------------------
__global__ __launch_bounds__(256) void lstm_step(const float* __restrict__ x_t,
                                                 const float* __restrict__ h_prev,
                                                 const float* __restrict__ W,
                                                 const float* __restrict__ bias,
                                                 const float* __restrict__ c_in,
                                                 float* __restrict__ c_out,
                                                 float* __restrict__ h_out,
                                                 float* __restrict__ hf,
                                                 float* __restrict__ cf, int last) {
    const int tid = threadIdx.x;
    const int hcc = tid & 7, b = tid >> 3;
    const int col = blockIdx.x * 8 + hcc;
    float a0 = bias[col], a1 = bias[col + 512], a2 = bias[col + 1024], a3 = bias[col + 1536];
    const float* xr = x_t + (size_t)b * IN_DIM;
    const float* hr = h_prev + (size_t)b * H_DIM;
    for (int k = 0; k < IN_DIM; ++k) {
        const float v = xr[k];
        const float* wk = &W[(size_t)k * G4 + col];
        a0 += v * wk[0]; a1 += v * wk[512]; a2 += v * wk[1024]; a3 += v * wk[1536];
    }
    for (int k = 0; k < H_DIM; ++k) {
        const float v = hr[k];
        const float* wk = &W[(size_t)(512 + k) * G4 + col];
        a0 += v * wk[0]; a1 += v * wk[512]; a2 += v * wk[1024]; a3 += v * wk[1536];
    }
    const float cn = sigm(a0) * c_in[(size_t)b * H_DIM + col] + sigm(a1) * tanhf(a2);
    const float hn = sigm(a3) * tanhf(cn);
    c_out[(size_t)b * H_DIM + col] = cn;
    h_out[(size_t)b * H_DIM + col] = hn;
    if (last) { hf[(size_t)b * H_DIM + col] = hn; cf[(size_t)b * H_DIM + col] = cn; }
}

extern "C" void kernel_launch(void* const* d_in, const int* in_sizes, int n_in,
                              void* d_out, int out_size, void* d_ws, size_t ws_size,
                              hipStream_t stream) {
    const float* x    = (const float*)d_in[0];
    const float* h0   = (const float*)d_in[1];
    const float* c0   = (const float*)d_in[2];
    const float* W    = (const float*)d_in[3];
    const float* bias = (const float*)d_in[4];

    float* outs = (float*)d_out;
    float* hf   = outs + (size_t)T_STEPS * BATCH * H_DIM;
    float* cf   = hf + BATCH * H_DIM;

    // pre16 256 MiB + Wt 4 MiB + hbuf 64 KiB + flags 4 KiB = 272.7 MB
    // (< proven-available 536.9 MB)
    const size_t OFF_WT = 268435456ull;
    const size_t OFF_HB = OFF_WT + 4194304ull;
    const size_t OFF_FL = OFF_HB + 65536ull;
    const size_t NEED   = OFF_FL + 4096ull;

    if (ws_size >= NEED) {
        _Float16* pre16     = (_Float16*)d_ws;
        unsigned short* Wt  = (unsigned short*)((char*)d_ws + OFF_WT);
        unsigned short* hb  = (unsigned short*)((char*)d_ws + OFF_HB);
        unsigned int* flags = (unsigned int*)((char*)d_ws + OFF_FL);

        hipMemsetAsync(flags, 0, 4096, stream);
        wt_kernel<<<dim3(64, 32), 256, 0, stream>>>(W, Wt);
        init_h<<<64, 256, 0, stream>>>(h0, hb);
        xw_mfma<<<dim3(32, 1024), 256, 0, stream>>>(x, Wt, bias, pre16);
        lstm_scan<<<NWG, NTHR, 0, stream>>>(Wt, (const unsigned short*)pre16,
                                            c0, hb, outs, hf, cf, flags);
    } else {
        float* c_ws = (float*)d_ws;
        for (int t = 0; t < T_STEPS; ++t) {
            const float* hp = t ? outs + (size_t)(t - 1) * BATCH * H_DIM : h0;
            const float* ci = t ? c_ws : c0;
            lstm_step<<<64, 256, 0, stream>>>(x + (size_t)t * BATCH * IN_DIM,
                                              hp, W, bias, ci, c_ws,
                                              outs + (size_t)t * BATCH * H_DIM,
                                              hf, cf, (t == T_STEPS - 1) ? 1 : 0);
        }
    }
}